// Round 1
// baseline (215.414 us; speedup 1.0000x reference)
//
#include <hip/hip_runtime.h>

// CIN cross-network, fused MFMA implementation (f16 inputs, fp32 accum).
//
// y[b,n,d] = relu( sum_{m,h} x0[b,m,d] * xk[b,h,d] * W[m,h,n] )
// out[b, 64*l + n] = sum_d y  (per layer l)
//
// GEMM view per batch: rows = 16 d's, cols n = 64, K = m*H + h (1024 or 2048).
// A[d][m*H+h] = x0[m,d]*xk[h,d] built on the fly; B = W repacked to per-lane
// fragment order by prep_w into d_ws (f16).
//
// Per-wave: 4 private batches, LDS wave-private => NO barriers anywhere.

typedef _Float16 half8 __attribute__((ext_vector_type(8)));
typedef float f32x4 __attribute__((ext_vector_type(4)));

#define OUT_STRIDE 192

// Repack W (fp32, [m][h][n], n stride 64) into f16 fragment order:
// dst[((t*NKB + kb)*64 + lane)*8 + j] = W[k=kb*32+q*8+j -> (m,h)][n=t*16+r]
// so a wave's B-frag load is base + lane*16B (one coalesced dwordx4).
__global__ void prep_w(const float* __restrict__ W, _Float16* __restrict__ dst,
                       int K, int logH, int nkbLog) {
  int e = blockIdx.x * 256 + threadIdx.x;   // e < K*64
  int j = e & 7;
  int lane = (e >> 3) & 63;
  int rr = lane & 15, qq = lane >> 4;
  int rest = e >> 9;
  int nkb = K >> 5;
  int kb = rest & (nkb - 1);
  int t = rest >> nkbLog;
  int k = kb * 32 + qq * 8 + j;
  int H = 1 << logH;
  int m = k >> logH, h = k & (H - 1);
  int n = t * 16 + rr;
  dst[e] = (_Float16)W[(m * H + h) * 64 + n];
}

// One layer for one wave's 4 private batches.
// LOGH: log2(H) (5 or 6). NKB = K/32 = H. VROW/VBSTR: f16 strides of the
// vector-source LDS region (x0: 40/640, xk: 72/1152).
template<int LOGH, int VROW, int VBSTR, bool LAST>
__device__ __forceinline__ void run_layer(
    const _Float16* __restrict__ Wp, const _Float16* vsrc,
    const _Float16* x0s, _Float16* xkdst, float* __restrict__ out,
    long gb0, int loff, int lane, int r, int q)
{
  const int NKB = 1 << LOGH;
  f32x4 acc[4][4];
#pragma unroll
  for (int b = 0; b < 4; ++b)
#pragma unroll
    for (int t = 0; t < 4; ++t) acc[b][t] = (f32x4){0.f, 0.f, 0.f, 0.f};

#pragma unroll 2
  for (int kb = 0; kb < NKB; ++kb) {
    const int m  = kb >> (LOGH - 5);
    const int h0 = (kb & ((1 << (LOGH - 5)) - 1)) << 5;
    half8 Bf[4];
#pragma unroll
    for (int t = 0; t < 4; ++t)
      Bf[t] = *(const half8*)(Wp + ((size_t)(t * NKB + kb) * 64 + lane) * 8);
#pragma unroll
    for (int b = 0; b < 4; ++b) {
      // A-frag: row d = r (= lane&15), k = q*8 + j within this 32-k block.
      half8 av = *(const half8*)(vsrc + b * VBSTR + r * VROW + h0 + q * 8);
      _Float16 xs = x0s[b * 640 + r * 40 + m];
      half8 xv;
#pragma unroll
      for (int j = 0; j < 8; ++j) xv[j] = xs;
      half8 af = av * xv;
#pragma unroll
      for (int t = 0; t < 4; ++t)
        acc[b][t] = __builtin_amdgcn_mfma_f32_16x16x32_f16(af, Bf[t], acc[b][t], 0, 0, 0);
    }
  }

  // Epilogue: C/D layout col=lane&15 (n within tile), row=q*4+reg (d).
#pragma unroll
  for (int b = 0; b < 4; ++b) {
#pragma unroll
    for (int t = 0; t < 4; ++t) {
      float s = 0.f;
#pragma unroll
      for (int rr = 0; rr < 4; ++rr) {
        float v = acc[b][t][rr];
        v = v > 0.f ? v : 0.f;
        s += v;
        if (!LAST)
          xkdst[b * 1152 + (q * 4 + rr) * 72 + t * 16 + r] = (_Float16)v;
      }
      s += __shfl_xor(s, 16);
      s += __shfl_xor(s, 32);
      if (q == 0)
        out[(gb0 + b) * OUT_STRIDE + loff + t * 16 + r] = s;
    }
  }
}

__global__ __launch_bounds__(256, 2) void cin_main(
    const float* __restrict__ emb, const _Float16* __restrict__ Wall,
    float* __restrict__ out)
{
  // x0: 16 batches * 16 d * 40 f16 (pad 32->40: 16B-aligned rows, spread banks)
  // xk: 16 batches * 16 d * 72 f16 (pad 64->72)
  __shared__ __align__(16) _Float16 lds[28672];
  const int lane = threadIdx.x & 63;
  const int wv = threadIdx.x >> 6;
  const int r = lane & 15, q = lane >> 4;
  const int lb0 = wv * 4;
  const long gb0 = (long)blockIdx.x * 16 + lb0;

  _Float16* x0b = &lds[lb0 * 640];
  _Float16* xkb = &lds[10240 + lb0 * 1152];

  // Stage this wave's 4 batches: read (m,d) fp32, write transposed (d,m) f16.
#pragma unroll
  for (int bb = 0; bb < 4; ++bb) {
    const float* src = emb + (gb0 + bb) * 512;
    _Float16* dstb = x0b + bb * 640;
#pragma unroll
    for (int i = 0; i < 2; ++i) {
      int f = i * 256 + lane * 4;         // flat = m*16 + d, d aligned to 4
      float4 v = *(const float4*)(src + f);
      int m = f >> 4, d = f & 15;
      dstb[(d + 0) * 40 + m] = (_Float16)v.x;
      dstb[(d + 1) * 40 + m] = (_Float16)v.y;
      dstb[(d + 2) * 40 + m] = (_Float16)v.z;
      dstb[(d + 3) * 40 + m] = (_Float16)v.w;
    }
  }
  // All LDS regions are wave-private: program order + waitcnt suffice.

  run_layer<5, 40,  640, false>(Wall,           x0b, x0b, xkb, out, gb0, 0,   lane, r, q);
  run_layer<6, 72, 1152, false>(Wall + 65536,   xkb, x0b, xkb, out, gb0, 64,  lane, r, q);
  run_layer<6, 72, 1152, true >(Wall + 196608,  xkb, x0b, xkb, out, gb0, 128, lane, r, q);
}

extern "C" void kernel_launch(void* const* d_in, const int* in_sizes, int n_in,
                              void* d_out, int out_size, void* d_ws, size_t ws_size,
                              hipStream_t stream) {
  const float* emb = (const float*)d_in[0];
  const float* W0  = (const float*)d_in[1];
  const float* W1  = (const float*)d_in[2];
  const float* W2  = (const float*)d_in[3];
  float* out = (float*)d_out;
  _Float16* ws = (_Float16*)d_ws;   // needs 327680 f16 = 640 KB

  // Repack weights to fragment order (f16) in workspace.
  prep_w<<<256, 256, 0, stream>>>(W0, ws,          1024, 5, 5);
  prep_w<<<512, 256, 0, stream>>>(W1, ws + 65536,  2048, 6, 6);
  prep_w<<<512, 256, 0, stream>>>(W2, ws + 196608, 2048, 6, 6);

  // 16384 batches / 16 per block = 1024 blocks of 256 threads (4 waves x 4 b).
  cin_main<<<1024, 256, 0, stream>>>(emb, ws, out);
}